// Round 12
// baseline (78.576 us; speedup 1.0000x reference)
//
#include <hip/hip_runtime.h>
#include <hip/hip_bf16.h>

#define BB 32
#define LL 100
#define DD 200      // MEM
#define KIN 360
#define NP 3200
#define RNUM 40
#define LT 8
#define NT 13       // l-tiles of 8 (last = 4)

typedef float vf4 __attribute__((ext_vector_type(4)));   // native vector for nt-store

__device__ __forceinline__ void nt_store4(float4 v, float4* p) {
    vf4 nv = {v.x, v.y, v.z, v.w};
    __builtin_nontemporal_store(nv, (vf4*)p);
}

__device__ __forceinline__ void fma4(float4& a, const float4& w, float s) {
    a.x = fmaf(w.x, s, a.x);
    a.y = fmaf(w.y, s, a.y);
    a.z = fmaf(w.z, s, a.z);
    a.w = fmaf(w.w, s, a.w);
}
// RTNE f32 -> bf16
__device__ __forceinline__ unsigned bf16rn(float f) {
    unsigned u = __float_as_uint(f);
    return (u + 0x7fffu + ((u >> 16) & 1u)) >> 16;
}
__device__ __forceinline__ unsigned pk2(float a, float b) {
    return bf16rn(a) | (bf16rn(b) << 16);
}
__device__ __forceinline__ float lo16(unsigned u) { return __uint_as_float(u << 16); }
__device__ __forceinline__ float hi16(unsigned u) { return __uint_as_float(u & 0xffff0000u); }

// ---------------- kernel 1: WpT transpose only (critical-path head, tiny) ----------------
__global__ __launch_bounds__(512) void wpt_kernel(const float* __restrict__ Wp,
                                                  float* __restrict__ WpT) {
    int t = blockIdx.x * 512 + threadIdx.x;
    if (t < 18000) {                  // WpT: [360][200] quads
        int k = t / 50, o = (t % 50) * 4;
        float4 v;
        v.x = Wp[(size_t)(o + 0) * KIN + k];
        v.y = Wp[(size_t)(o + 1) * KIN + k];
        v.z = Wp[(size_t)(o + 2) * KIN + k];
        v.w = Wp[(size_t)(o + 3) * KIN + k];
        nt_store4(v, (float4*)WpT + t);   // clean lines for all-XCD readers
    }
}

// ---------------- kernel 2: embed+proj GEMV (0..399) | prep (400..431) | W0T/W1T (432..471) --
__global__ __launch_bounds__(512, 4) void embed_prep_kernel(
        const int* __restrict__ words, const int* __restrict__ pos, const int* __restrict__ ner,
        const float* __restrict__ emb, const float* __restrict__ pose, const float* __restrict__ nere,
        const float* __restrict__ wpt, const float* __restrict__ bp,
        const int* __restrict__ adj,
        const float* __restrict__ W0, const float* __restrict__ W1,
        float* __restrict__ W0T, float* __restrict__ W1T,
        float* __restrict__ xA, float* __restrict__ invd, float* __restrict__ mask_out) {
    __shared__ alignas(16) char smem[40960];
    int bid = blockIdx.x, tid = threadIdx.x;

    if (bid >= 432) {
        // ---- W0T / W1T transposes (consumed by the layer kernels on all XCDs) ----
        int i = (bid - 432) * 512 + tid;
        if (i < 10000) {                  // W0T
            int k = i / 50, o = (i % 50) * 4;
            float4 v;
            v.x = W0[(size_t)(o + 0) * DD + k];
            v.y = W0[(size_t)(o + 1) * DD + k];
            v.z = W0[(size_t)(o + 2) * DD + k];
            v.w = W0[(size_t)(o + 3) * DD + k];
            nt_store4(v, (float4*)W0T + i);
        } else if (i < 20000) {           // W1T
            int q = i - 10000;
            int k = q / 50, o = (q % 50) * 4;
            float4 v;
            v.x = W1[(size_t)(o + 0) * DD + k];
            v.y = W1[(size_t)(o + 1) * DD + k];
            v.z = W1[(size_t)(o + 2) * DD + k];
            v.w = W1[(size_t)(o + 3) * DD + k];
            nt_store4(v, (float4*)W1T + q);
        }
        return;
    }

    if (bid >= 400) {
        // ---- prep for batch bb: adj staged in LDS, row/col nonzero counts ----
        int bb = bid - 400;
        int* a_lds = (int*)smem;              // 40000 B
        int* rcc = (int*)(smem + 40000);      // 200 ints
        const int4* src = (const int4*)(adj + (size_t)bb * (LL * LL));
        for (int i = tid; i < 2500; i += 512) ((int4*)a_lds)[i] = src[i];
        __syncthreads();
        if (tid < 200) {
            int l = tid % 100;
            int c = 0;
            if (tid < 100) {
                #pragma unroll 4
                for (int m = 0; m < 100; ++m) c += (a_lds[l * 100 + m] != 0);
            } else {
                #pragma unroll 4
                for (int m = 0; m < 100; ++m) c += (a_lds[m * 100 + l] != 0);
            }
            rcc[tid] = c;
        }
        __syncthreads();
        if (tid < 100) {
            int rc = rcc[tid], cc = rcc[100 + tid];
            __builtin_nontemporal_store(1.0f / (float)(rc + 1), invd + bb * 100 + tid);
            __builtin_nontemporal_store((rc + cc == 0) ? 1.0f : 0.0f,
                                        mask_out + bb * 100 + tid);
        }
        return;
    }

    // ---- embed + projection GEMV ----
    float* es = (float*)smem;                    // 11520 B
    float4* red = (float4*)(smem + 11520);       // 4 slots x 400 quads = 25600 B
    int pbase = bid * 8;

    float2* es2 = (float2*)es;
    for (int idx = tid; idx < 8 * 180; idx += 512) {
        int p = idx / 180, j2 = idx % 180;
        int gp = pbase + p;
        float2 v;
        if (j2 < 150)      v = ((const float2*)emb)[(size_t)words[gp] * 150 + j2];
        else if (j2 < 165) v = ((const float2*)pose)[pos[gp] * 15 + (j2 - 150)];
        else               v = ((const float2*)nere)[ner[gp] * 15 + (j2 - 165)];
        es2[idx] = v;
    }
    __syncthreads();

    int lane = tid & 63, w = tid >> 6;   // 8 waves
    bool act = lane < 50;
    int oq = act ? lane : 49;
    int kq0 = (w < 5) ? 12 * w : 60 + 10 * (w - 5);
    int npair = (w < 5) ? 6 : 5;         // all chunks even
    int kqlast = kq0 + 2 * npair - 1;
    const float4* wt4 = (const float4*)wpt;
    const float4* es4 = (const float4*)es;

    float4 a[8];
    #pragma unroll
    for (int p = 0; p < 8; ++p) a[p] = make_float4(0.f, 0.f, 0.f, 0.f);

    float4 wc[8], wn[8];
    #pragma unroll
    for (int q = 0; q < 2; ++q)
        #pragma unroll
        for (int j = 0; j < 4; ++j)
            wc[q * 4 + j] = wt4[(size_t)(4 * (kq0 + q) + j) * 50 + oq];

    for (int pr = 0; pr < npair; ++pr) {
        int nb = kq0 + 2 * pr + 2;
        int nbA = nb <= kqlast ? nb : kq0;
        int nbB = nb + 1 <= kqlast ? nb + 1 : kq0;
        #pragma unroll
        for (int j = 0; j < 4; ++j) wn[j]     = wt4[(size_t)(4 * nbA + j) * 50 + oq];
        #pragma unroll
        for (int j = 0; j < 4; ++j) wn[4 + j] = wt4[(size_t)(4 * nbB + j) * 50 + oq];
        #pragma unroll
        for (int q = 0; q < 2; ++q) {
            int kq = kq0 + 2 * pr + q;
            #pragma unroll
            for (int p = 0; p < 8; ++p) {
                float4 s = es4[p * 90 + kq];   // wave-uniform broadcast
                fma4(a[p], wc[q * 4 + 0], s.x); fma4(a[p], wc[q * 4 + 1], s.y);
                fma4(a[p], wc[q * 4 + 2], s.z); fma4(a[p], wc[q * 4 + 3], s.w);
            }
        }
        #pragma unroll
        for (int j = 0; j < 8; ++j) wc[j] = wn[j];
    }

    // two-stage 4-slot reduce
    if (w >= 4 && act) {
        #pragma unroll
        for (int p = 0; p < 8; ++p) red[(w - 4) * 400 + p * 50 + oq] = a[p];
    }
    __syncthreads();
    if (w < 4 && act) {
        #pragma unroll
        for (int p = 0; p < 8; ++p) {
            float4 r = red[w * 400 + p * 50 + oq];
            r.x += a[p].x; r.y += a[p].y; r.z += a[p].z; r.w += a[p].w;
            red[w * 400 + p * 50 + oq] = r;
        }
    }
    __syncthreads();
    for (int t = tid; t < 400; t += 512) {
        int oq2 = t % 50;
        float4 v = ((const float4*)bp)[oq2];
        #pragma unroll
        for (int s = 0; s < 4; ++s) {
            float4 r = red[s * 400 + t];
            v.x += r.x; v.y += r.y; v.z += r.z; v.w += r.w;
        }
        ((float4*)xA)[(size_t)(pbase + t / 50) * 50 + oq2] = v;
    }
}

// ---------------- kernel 3/4: fused layer, 1024 threads / 16 waves, LT=8 tiles ----------------
// Waves: lg = w&3 (l-group: l = lg+4i, i<2), sq = w>>2 (m-quarter for Ax, k-quarter for GEMV).
__global__ __launch_bounds__(1024, 4) void layer_kernel(
        const float* __restrict__ x, const int* __restrict__ adj,
        const float* __restrict__ deprel, const float* __restrict__ wt,
        const float* __restrict__ bias, const float* __restrict__ invd,
        float* __restrict__ out) {
    __shared__ alignas(16) char smem[42400];
    uint2* deps_b = (uint2*)smem;                 // [0, 16000)       Ax only
    unsigned* adjp = (unsigned*)(smem + 16000);   // [16000, 16800)   Ax only
    float4* Sh = (float4*)(smem + 16800);         // [16800, 42400)   4 slots x 400
    float4* Sfin = (float4*)smem;                 // [0, 6400)        overlays deps (dead)

    int b = blockIdx.y, tile = blockIdx.x;
    int l0 = tile * LT;
    int lcnt = min(LT, LL - l0);
    int tid = threadIdx.x;
    const float4* x4 = (const float4*)x;

    for (int i = tid; i < RNUM * 50; i += 1024) {
        float4 v = ((const float4*)deprel)[i];
        deps_b[i] = make_uint2(pk2(v.x, v.y), pk2(v.z, v.w));
    }
    for (int i = tid; i < lcnt * 25; i += 1024) {
        int li = i / 25, mg = i % 25;
        int4 a = ((const int4*)(adj + (size_t)(b * LL + l0 + li) * LL))[mg];
        adjp[i] = (unsigned)a.x | ((unsigned)a.y << 8) | ((unsigned)a.z << 16) | ((unsigned)a.w << 24);
    }
    __syncthreads();

    int lane = tid & 63, w = tid >> 6;   // 16 waves
    int lg = w & 3, sq = w >> 2;
    bool act = lane < 50;
    int dq = lane;

    // ---- Ax over m-quarter {7,6,6,6}, one-mg-ahead x prefetch, 2 rows/wave ----
    float4 acc[2];
    #pragma unroll
    for (int i = 0; i < 2; ++i) acc[i] = make_float4(0.f, 0.f, 0.f, 0.f);
    if (act) {
        int mg0 = (sq == 0) ? 0 : 1 + 6 * sq;       // 0,7,13,19
        int mg1 = mg0 + ((sq == 0) ? 7 : 6);
        float4 xc[4], xn[4];
        #pragma unroll
        for (int mm = 0; mm < 4; ++mm)
            xc[mm] = x4[(size_t)(b * LL + 4 * mg0 + mm) * 50 + dq];
        for (int mg = mg0; mg < mg1; ++mg) {
            int mgn = (mg + 1 < mg1) ? mg + 1 : mg;   // dummy reload on last iter
            #pragma unroll
            for (int mm = 0; mm < 4; ++mm)
                xn[mm] = x4[(size_t)(b * LL + 4 * mgn + mm) * 50 + dq];
            unsigned ap[2];
            #pragma unroll
            for (int i = 0; i < 2; ++i) {
                int li = lg + 4 * i;
                ap[i] = (li < lcnt) ? adjp[li * 25 + mg] : 0u;
            }
            #pragma unroll
            for (int mm = 0; mm < 4; ++mm) {
                #pragma unroll
                for (int i = 0; i < 2; ++i) {
                    unsigned r = (ap[i] >> (8 * mm)) & 0xffu;
                    uint2 dv = deps_b[r * 50 + dq];
                    acc[i].x = fmaf(lo16(dv.x), xc[mm].x, acc[i].x);
                    acc[i].y = fmaf(hi16(dv.x), xc[mm].y, acc[i].y);
                    acc[i].z = fmaf(lo16(dv.y), xc[mm].z, acc[i].z);
                    acc[i].w = fmaf(hi16(dv.y), xc[mm].w, acc[i].w);
                }
            }
            #pragma unroll
            for (int mm = 0; mm < 4; ++mm) xc[mm] = xn[mm];
        }
        #pragma unroll
        for (int i = 0; i < 2; ++i) {
            int li = lg + 4 * i;
            if (li < lcnt) Sh[sq * 400 + li * 50 + dq] = acc[i];
        }
    }
    __syncthreads();

    // ---- reduce 4 slots + fp32 residual -> Sfin (over dead deps region) ----
    for (int t2 = tid; t2 < 400; t2 += 1024) {
        int li = t2 / 50;
        if (li < lcnt) {
            float4 s0 = Sh[t2], s1 = Sh[400 + t2], s2 = Sh[800 + t2], s3 = Sh[1200 + t2];
            float4 xr = x4[(size_t)(b * LL + l0 + li) * 50 + (t2 % 50)];
            float4 s;
            s.x = s0.x + s1.x + s2.x + s3.x + xr.x;
            s.y = s0.y + s1.y + s2.y + s3.y + xr.y;
            s.z = s0.z + s1.z + s2.z + s3.z + xr.z;
            s.w = s0.w + s1.w + s2.w + s3.w + xr.w;
            Sfin[t2] = s;
        }
    }
    __syncthreads();

    // ---- GEMV over k-quarter {13,13,12,12}, transposed-W coalesced reads, pipelined ----
    const float4* wt4 = (const float4*)wt;
    int oq = act ? lane : 49;
    int kq0 = (sq < 2) ? 13 * sq : 26 + 12 * (sq - 2);  // 0,13,26,38
    int kcnt = (sq < 2) ? 13 : 12;
    int npair = kcnt >> 1;                              // 6
    int kqlast = kq0 + kcnt - 1;
    float4 ba[2];
    #pragma unroll
    for (int i = 0; i < 2; ++i) ba[i] = make_float4(0.f, 0.f, 0.f, 0.f);

    float4 wc[8], wn[8];
    #pragma unroll
    for (int q = 0; q < 2; ++q)
        #pragma unroll
        for (int j = 0; j < 4; ++j)
            wc[q * 4 + j] = wt4[(size_t)(4 * (kq0 + q) + j) * 50 + oq];

    int lic[2];
    #pragma unroll
    for (int i = 0; i < 2; ++i) {
        int li = lg + 4 * i;
        lic[i] = li < lcnt ? li : lcnt - 1;
    }

    for (int pr = 0; pr < npair; ++pr) {
        int nb = kq0 + 2 * pr + 2;
        int nbA = nb <= kqlast ? nb : kq0;
        int nbB = nb + 1 <= kqlast ? nb + 1 : kq0;
        #pragma unroll
        for (int j = 0; j < 4; ++j) wn[j]     = wt4[(size_t)(4 * nbA + j) * 50 + oq];
        #pragma unroll
        for (int j = 0; j < 4; ++j) wn[4 + j] = wt4[(size_t)(4 * nbB + j) * 50 + oq];
        #pragma unroll
        for (int q = 0; q < 2; ++q) {
            int kq = kq0 + 2 * pr + q;
            #pragma unroll
            for (int i = 0; i < 2; ++i) {
                float4 s = Sfin[lic[i] * 50 + kq];   // wave-uniform broadcast
                fma4(ba[i], wc[q * 4 + 0], s.x); fma4(ba[i], wc[q * 4 + 1], s.y);
                fma4(ba[i], wc[q * 4 + 2], s.z); fma4(ba[i], wc[q * 4 + 3], s.w);
            }
        }
        #pragma unroll
        for (int j = 0; j < 8; ++j) wc[j] = wn[j];
    }
    if (kcnt & 1) {   // tail quad kqlast (sits in wc[0..3] after final prefetch)
        #pragma unroll
        for (int i = 0; i < 2; ++i) {
            float4 s = Sfin[lic[i] * 50 + kqlast];
            fma4(ba[i], wc[0], s.x); fma4(ba[i], wc[1], s.y);
            fma4(ba[i], wc[2], s.z); fma4(ba[i], wc[3], s.w);
        }
    }

    if (act) {
        #pragma unroll
        for (int i = 0; i < 2; ++i) {
            int li = lg + 4 * i;
            if (li < lcnt) Sh[sq * 400 + li * 50 + oq] = ba[i];
        }
    }
    __syncthreads();

    for (int t2 = tid; t2 < 400; t2 += 1024) {
        int li = t2 / 50, oq2 = t2 % 50;
        if (li < lcnt) {
            float4 v0 = Sh[t2], v1 = Sh[400 + t2], v2 = Sh[800 + t2], v3 = Sh[1200 + t2];
            float4 bb = ((const float4*)bias)[oq2];
            int p = b * LL + l0 + li;
            float sc = invd[p];
            float4 v;
            v.x = fmaxf((v0.x + v1.x + v2.x + v3.x + 2.f * bb.x) * sc, 0.f);
            v.y = fmaxf((v0.y + v1.y + v2.y + v3.y + 2.f * bb.y) * sc, 0.f);
            v.z = fmaxf((v0.z + v1.z + v2.z + v3.z + 2.f * bb.z) * sc, 0.f);
            v.w = fmaxf((v0.w + v1.w + v2.w + v3.w + 2.f * bb.w) * sc, 0.f);
            ((float4*)out)[(size_t)p * 50 + oq2] = v;
        }
    }
}

extern "C" void kernel_launch(void* const* d_in, const int* in_sizes, int n_in,
                              void* d_out, int out_size, void* d_ws, size_t ws_size,
                              hipStream_t stream) {
    const int*   adj   = (const int*)d_in[0];
    const int*   words = (const int*)d_in[1];
    const int*   pos   = (const int*)d_in[2];
    const int*   ner   = (const int*)d_in[3];
    const float* emb   = (const float*)d_in[4];
    const float* pose  = (const float*)d_in[5];
    const float* nere  = (const float*)d_in[6];
    const float* dep   = (const float*)d_in[7];
    const float* Wp    = (const float*)d_in[8];
    const float* bp    = (const float*)d_in[9];
    const float* W0    = (const float*)d_in[10];
    const float* b0    = (const float*)d_in[11];
    const float* W1    = (const float*)d_in[12];
    const float* b1    = (const float*)d_in[13];
    float* out = (float*)d_out;
    float* ws  = (float*)d_ws;

    float* xA   = ws;                // 640,000
    float* xB   = ws + 640000;       // 640,000
    float* WpT  = ws + 1280000;      //  72,000
    float* W0T  = ws + 1352000;      //  40,000
    float* W1T  = ws + 1392000;      //  40,000
    float* invd = ws + 1432000;      //   3,200

    wpt_kernel<<<36, 512, 0, stream>>>(Wp, WpT);
    embed_prep_kernel<<<472, 512, 0, stream>>>(words, pos, ner, emb, pose, nere,
                                               WpT, bp, adj, W0, W1, W0T, W1T,
                                               xA, invd, out + (size_t)NP * DD);
    layer_kernel<<<dim3(NT, BB), 1024, 0, stream>>>(xA, adj, dep, W0T, b0, invd, xB);
    layer_kernel<<<dim3(NT, BB), 1024, 0, stream>>>(xB, adj, dep, W1T, b1, invd, out);
}

// Round 13
// 61.514 us; speedup vs baseline: 1.2774x; 1.2774x over previous
//
#include <hip/hip_runtime.h>
#include <hip/hip_bf16.h>

#define BB 32
#define LL 100
#define DD 200      // MEM
#define KIN 360
#define NP 3200
#define RNUM 40
#define LT 13
#define NT 8        // l-tiles of 13 (last = 9)

__device__ __forceinline__ void fma4(float4& a, const float4& w, float s) {
    a.x = fmaf(w.x, s, a.x);
    a.y = fmaf(w.y, s, a.y);
    a.z = fmaf(w.z, s, a.z);
    a.w = fmaf(w.w, s, a.w);
}
// RTNE f32 -> bf16
__device__ __forceinline__ unsigned bf16rn(float f) {
    unsigned u = __float_as_uint(f);
    return (u + 0x7fffu + ((u >> 16) & 1u)) >> 16;
}
__device__ __forceinline__ unsigned pk2(float a, float b) {
    return bf16rn(a) | (bf16rn(b) << 16);
}
__device__ __forceinline__ float lo16(unsigned u) { return __uint_as_float(u << 16); }
__device__ __forceinline__ float hi16(unsigned u) { return __uint_as_float(u & 0xffff0000u); }

// ---------------- kernel 1: WpT transpose only (critical-path head, tiny) ----------------
__global__ __launch_bounds__(512) void wpt_kernel(const float* __restrict__ Wp,
                                                  float* __restrict__ WpT) {
    int t = blockIdx.x * 512 + threadIdx.x;
    if (t < 18000) {                  // WpT: [360][200] quads
        int k = t / 50, o = (t % 50) * 4;
        float4 v;
        v.x = Wp[(size_t)(o + 0) * KIN + k];
        v.y = Wp[(size_t)(o + 1) * KIN + k];
        v.z = Wp[(size_t)(o + 2) * KIN + k];
        v.w = Wp[(size_t)(o + 3) * KIN + k];
        ((float4*)WpT)[t] = v;
    }
}

// -------- kernel 2: embed+proj (0..399) | prep (400..431) | W0T/W1T (432..471)
//          | deprel pack (472..475) | adj byte-pack (476..632) --------
__global__ __launch_bounds__(512, 4) void embed_prep_kernel(
        const int* __restrict__ words, const int* __restrict__ pos, const int* __restrict__ ner,
        const float* __restrict__ emb, const float* __restrict__ pose, const float* __restrict__ nere,
        const float* __restrict__ wpt, const float* __restrict__ bp,
        const int* __restrict__ adj, const float* __restrict__ dep,
        const float* __restrict__ W0, const float* __restrict__ W1,
        float* __restrict__ W0T, float* __restrict__ W1T,
        uint2* __restrict__ depp_g, unsigned* __restrict__ adjp_g,
        float* __restrict__ xA, float* __restrict__ invd, float* __restrict__ mask_out) {
    __shared__ alignas(16) char smem[40960];
    int bid = blockIdx.x, tid = threadIdx.x;

    if (bid >= 476) {
        // ---- adj byte-pack: 80000 u32 items (3200 rows x 25 quads) ----
        int i = (bid - 476) * 512 + tid;
        if (i < 80000) {
            int4 a = ((const int4*)adj)[i];
            adjp_g[i] = (unsigned)a.x | ((unsigned)a.y << 8) |
                        ((unsigned)a.z << 16) | ((unsigned)a.w << 24);
        }
        return;
    }
    if (bid >= 472) {
        // ---- deprel bf16 pack: 2000 uint2 items ----
        int i = (bid - 472) * 512 + tid;
        if (i < 2000) {
            float4 v = ((const float4*)dep)[i];
            depp_g[i] = make_uint2(pk2(v.x, v.y), pk2(v.z, v.w));
        }
        return;
    }
    if (bid >= 432) {
        // ---- W0T / W1T transposes ----
        int i = (bid - 432) * 512 + tid;
        if (i < 10000) {                  // W0T
            int k = i / 50, o = (i % 50) * 4;
            float4 v;
            v.x = W0[(size_t)(o + 0) * DD + k];
            v.y = W0[(size_t)(o + 1) * DD + k];
            v.z = W0[(size_t)(o + 2) * DD + k];
            v.w = W0[(size_t)(o + 3) * DD + k];
            ((float4*)W0T)[i] = v;
        } else if (i < 20000) {           // W1T
            int q = i - 10000;
            int k = q / 50, o = (q % 50) * 4;
            float4 v;
            v.x = W1[(size_t)(o + 0) * DD + k];
            v.y = W1[(size_t)(o + 1) * DD + k];
            v.z = W1[(size_t)(o + 2) * DD + k];
            v.w = W1[(size_t)(o + 3) * DD + k];
            ((float4*)W1T)[q] = v;
        }
        return;
    }

    if (bid >= 400) {
        // ---- prep for batch bb: adj staged in LDS, row/col nonzero counts ----
        int bb = bid - 400;
        int* a_lds = (int*)smem;              // 40000 B
        int* rcc = (int*)(smem + 40000);      // 200 ints
        const int4* src = (const int4*)(adj + (size_t)bb * (LL * LL));
        for (int i = tid; i < 2500; i += 512) ((int4*)a_lds)[i] = src[i];
        __syncthreads();
        if (tid < 200) {
            int l = tid % 100;
            int c = 0;
            if (tid < 100) {
                #pragma unroll 4
                for (int m = 0; m < 100; ++m) c += (a_lds[l * 100 + m] != 0);
            } else {
                #pragma unroll 4
                for (int m = 0; m < 100; ++m) c += (a_lds[m * 100 + l] != 0);
            }
            rcc[tid] = c;
        }
        __syncthreads();
        if (tid < 100) {
            int rc = rcc[tid], cc = rcc[100 + tid];
            invd[bb * 100 + tid] = 1.0f / (float)(rc + 1);
            mask_out[bb * 100 + tid] = (rc + cc == 0) ? 1.0f : 0.0f;
        }
        return;
    }

    // ---- embed + projection GEMV ----
    float* es = (float*)smem;                    // 11520 B
    float4* red = (float4*)(smem + 11520);       // 4 slots x 400 quads = 25600 B
    int pbase = bid * 8;

    float2* es2 = (float2*)es;
    for (int idx = tid; idx < 8 * 180; idx += 512) {
        int p = idx / 180, j2 = idx % 180;
        int gp = pbase + p;
        float2 v;
        if (j2 < 150)      v = ((const float2*)emb)[(size_t)words[gp] * 150 + j2];
        else if (j2 < 165) v = ((const float2*)pose)[pos[gp] * 15 + (j2 - 150)];
        else               v = ((const float2*)nere)[ner[gp] * 15 + (j2 - 165)];
        es2[idx] = v;
    }
    __syncthreads();

    int lane = tid & 63, w = tid >> 6;   // 8 waves
    bool act = lane < 50;
    int oq = act ? lane : 49;
    int kq0 = (w < 5) ? 12 * w : 60 + 10 * (w - 5);
    int npair = (w < 5) ? 6 : 5;         // all chunks even
    int kqlast = kq0 + 2 * npair - 1;
    const float4* wt4 = (const float4*)wpt;
    const float4* es4 = (const float4*)es;

    float4 a[8];
    #pragma unroll
    for (int p = 0; p < 8; ++p) a[p] = make_float4(0.f, 0.f, 0.f, 0.f);

    float4 wc[8], wn[8];
    #pragma unroll
    for (int q = 0; q < 2; ++q)
        #pragma unroll
        for (int j = 0; j < 4; ++j)
            wc[q * 4 + j] = wt4[(size_t)(4 * (kq0 + q) + j) * 50 + oq];

    for (int pr = 0; pr < npair; ++pr) {
        int nb = kq0 + 2 * pr + 2;
        int nbA = nb <= kqlast ? nb : kq0;
        int nbB = nb + 1 <= kqlast ? nb + 1 : kq0;
        #pragma unroll
        for (int j = 0; j < 4; ++j) wn[j]     = wt4[(size_t)(4 * nbA + j) * 50 + oq];
        #pragma unroll
        for (int j = 0; j < 4; ++j) wn[4 + j] = wt4[(size_t)(4 * nbB + j) * 50 + oq];
        #pragma unroll
        for (int q = 0; q < 2; ++q) {
            int kq = kq0 + 2 * pr + q;
            #pragma unroll
            for (int p = 0; p < 8; ++p) {
                float4 s = es4[p * 90 + kq];   // wave-uniform broadcast
                fma4(a[p], wc[q * 4 + 0], s.x); fma4(a[p], wc[q * 4 + 1], s.y);
                fma4(a[p], wc[q * 4 + 2], s.z); fma4(a[p], wc[q * 4 + 3], s.w);
            }
        }
        #pragma unroll
        for (int j = 0; j < 8; ++j) wc[j] = wn[j];
    }

    // two-stage 4-slot reduce
    if (w >= 4 && act) {
        #pragma unroll
        for (int p = 0; p < 8; ++p) red[(w - 4) * 400 + p * 50 + oq] = a[p];
    }
    __syncthreads();
    if (w < 4 && act) {
        #pragma unroll
        for (int p = 0; p < 8; ++p) {
            float4 r = red[w * 400 + p * 50 + oq];
            r.x += a[p].x; r.y += a[p].y; r.z += a[p].z; r.w += a[p].w;
            red[w * 400 + p * 50 + oq] = r;
        }
    }
    __syncthreads();
    for (int t = tid; t < 400; t += 512) {
        int oq2 = t % 50;
        float4 v = ((const float4*)bp)[oq2];
        #pragma unroll
        for (int s = 0; s < 4; ++s) {
            float4 r = red[s * 400 + t];
            v.x += r.x; v.y += r.y; v.z += r.z; v.w += r.w;
        }
        ((float4*)xA)[(size_t)(pbase + t / 50) * 50 + oq2] = v;
    }
}

// ---------------- kernel 3/4: fused layer, 1024 threads / 16 waves (R10 body, pre-packed) --
// Waves: lg = w&3 (l-group: l = lg+4i), sq = w>>2 (m-quarter for Ax, k-quarter for GEMV).
__global__ __launch_bounds__(1024, 4) void layer_kernel(
        const float* __restrict__ x,
        const uint2* __restrict__ depp_g, const unsigned* __restrict__ adjp_g,
        const float* __restrict__ wt, const float* __restrict__ bias,
        const float* __restrict__ invd, float* __restrict__ out) {
    __shared__ alignas(16) char smem[58912];
    uint2* deps_b = (uint2*)smem;                 // [0, 16000)       Ax only
    unsigned* adjp = (unsigned*)(smem + 16000);   // [16000, 17300)   Ax only
    float4* Sh = (float4*)(smem + 17312);         // [17312, 58912)   4 slots x 650
    float4* Sfin = (float4*)smem;                 // [0, 10400)       overlays deps (dead)

    int b = blockIdx.y, tile = blockIdx.x;
    int l0 = tile * LT;
    int lcnt = min(LT, LL - l0);
    int tid = threadIdx.x;
    const float4* x4 = (const float4*)x;

    for (int i = tid; i < 2000; i += 1024) deps_b[i] = depp_g[i];           // pre-packed
    for (int i = tid; i < lcnt * 25; i += 1024)
        adjp[i] = adjp_g[(b * LL + l0) * 25 + i];                           // pre-packed
    __syncthreads();

    int lane = tid & 63, w = tid >> 6;   // 16 waves
    int lg = w & 3, sq = w >> 2;
    bool act = lane < 50;
    int dq = lane;

    // ---- Ax over m-quarter {7,6,6,6}, one-mg-ahead x prefetch ----
    float4 acc[4];
    #pragma unroll
    for (int i = 0; i < 4; ++i) acc[i] = make_float4(0.f, 0.f, 0.f, 0.f);
    if (act) {
        int mg0 = (sq == 0) ? 0 : 1 + 6 * sq;       // 0,7,13,19
        int mg1 = mg0 + ((sq == 0) ? 7 : 6);
        float4 xc[4], xn[4];
        #pragma unroll
        for (int mm = 0; mm < 4; ++mm)
            xc[mm] = x4[(size_t)(b * LL + 4 * mg0 + mm) * 50 + dq];
        for (int mg = mg0; mg < mg1; ++mg) {
            int mgn = (mg + 1 < mg1) ? mg + 1 : mg;   // dummy reload on last iter
            #pragma unroll
            for (int mm = 0; mm < 4; ++mm)
                xn[mm] = x4[(size_t)(b * LL + 4 * mgn + mm) * 50 + dq];
            unsigned ap[4];
            #pragma unroll
            for (int i = 0; i < 4; ++i) {
                int li = lg + 4 * i;
                ap[i] = (li < lcnt) ? adjp[li * 25 + mg] : 0u;
            }
            #pragma unroll
            for (int mm = 0; mm < 4; ++mm) {
                #pragma unroll
                for (int i = 0; i < 4; ++i) {
                    unsigned r = (ap[i] >> (8 * mm)) & 0xffu;
                    uint2 dv = deps_b[r * 50 + dq];
                    acc[i].x = fmaf(lo16(dv.x), xc[mm].x, acc[i].x);
                    acc[i].y = fmaf(hi16(dv.x), xc[mm].y, acc[i].y);
                    acc[i].z = fmaf(lo16(dv.y), xc[mm].z, acc[i].z);
                    acc[i].w = fmaf(hi16(dv.y), xc[mm].w, acc[i].w);
                }
            }
            #pragma unroll
            for (int mm = 0; mm < 4; ++mm) xc[mm] = xn[mm];
        }
        #pragma unroll
        for (int i = 0; i < 4; ++i) {
            int li = lg + 4 * i;
            if (li < lcnt) Sh[sq * 650 + li * 50 + dq] = acc[i];
        }
    }
    __syncthreads();

    // ---- reduce 4 slots + fp32 residual -> Sfin (over dead deps region) ----
    for (int t2 = tid; t2 < 650; t2 += 1024) {
        int li = t2 / 50;
        if (li < lcnt) {
            float4 s0 = Sh[t2], s1 = Sh[650 + t2], s2 = Sh[1300 + t2], s3 = Sh[1950 + t2];
            float4 xr = x4[(size_t)(b * LL + l0 + li) * 50 + (t2 % 50)];
            float4 s;
            s.x = s0.x + s1.x + s2.x + s3.x + xr.x;
            s.y = s0.y + s1.y + s2.y + s3.y + xr.y;
            s.z = s0.z + s1.z + s2.z + s3.z + xr.z;
            s.w = s0.w + s1.w + s2.w + s3.w + xr.w;
            Sfin[t2] = s;
        }
    }
    __syncthreads();

    // ---- GEMV over k-quarter {13,13,12,12}, transposed-W coalesced reads, pipelined ----
    const float4* wt4 = (const float4*)wt;
    int oq = act ? lane : 49;
    int kq0 = (sq < 2) ? 13 * sq : 26 + 12 * (sq - 2);  // 0,13,26,38
    int kcnt = (sq < 2) ? 13 : 12;
    int npair = kcnt >> 1;                              // 6
    int kqlast = kq0 + kcnt - 1;
    float4 ba[4];
    #pragma unroll
    for (int i = 0; i < 4; ++i) ba[i] = make_float4(0.f, 0.f, 0.f, 0.f);

    float4 wc[8], wn[8];
    #pragma unroll
    for (int q = 0; q < 2; ++q)
        #pragma unroll
        for (int j = 0; j < 4; ++j)
            wc[q * 4 + j] = wt4[(size_t)(4 * (kq0 + q) + j) * 50 + oq];

    int lic[4];
    #pragma unroll
    for (int i = 0; i < 4; ++i) {
        int li = lg + 4 * i;
        lic[i] = li < lcnt ? li : lcnt - 1;
    }

    for (int pr = 0; pr < npair; ++pr) {
        int nb = kq0 + 2 * pr + 2;
        int nbA = nb <= kqlast ? nb : kq0;
        int nbB = nb + 1 <= kqlast ? nb + 1 : kq0;
        #pragma unroll
        for (int j = 0; j < 4; ++j) wn[j]     = wt4[(size_t)(4 * nbA + j) * 50 + oq];
        #pragma unroll
        for (int j = 0; j < 4; ++j) wn[4 + j] = wt4[(size_t)(4 * nbB + j) * 50 + oq];
        #pragma unroll
        for (int q = 0; q < 2; ++q) {
            int kq = kq0 + 2 * pr + q;
            #pragma unroll
            for (int i = 0; i < 4; ++i) {
                float4 s = Sfin[lic[i] * 50 + kq];   // wave-uniform broadcast
                fma4(ba[i], wc[q * 4 + 0], s.x); fma4(ba[i], wc[q * 4 + 1], s.y);
                fma4(ba[i], wc[q * 4 + 2], s.z); fma4(ba[i], wc[q * 4 + 3], s.w);
            }
        }
        #pragma unroll
        for (int j = 0; j < 8; ++j) wc[j] = wn[j];
    }
    if (kcnt & 1) {   // tail quad kqlast (sits in wc[0..3] after final prefetch)
        #pragma unroll
        for (int i = 0; i < 4; ++i) {
            float4 s = Sfin[lic[i] * 50 + kqlast];
            fma4(ba[i], wc[0], s.x); fma4(ba[i], wc[1], s.y);
            fma4(ba[i], wc[2], s.z); fma4(ba[i], wc[3], s.w);
        }
    }

    if (act) {
        #pragma unroll
        for (int i = 0; i < 4; ++i) {
            int li = lg + 4 * i;
            if (li < lcnt) Sh[sq * 650 + li * 50 + oq] = ba[i];
        }
    }
    __syncthreads();

    for (int t2 = tid; t2 < 650; t2 += 1024) {
        int li = t2 / 50, oq2 = t2 % 50;
        if (li < lcnt) {
            float4 v0 = Sh[t2], v1 = Sh[650 + t2], v2 = Sh[1300 + t2], v3 = Sh[1950 + t2];
            float4 bb = ((const float4*)bias)[oq2];
            int p = b * LL + l0 + li;
            float sc = invd[p];
            float4 v;
            v.x = fmaxf((v0.x + v1.x + v2.x + v3.x + 2.f * bb.x) * sc, 0.f);
            v.y = fmaxf((v0.y + v1.y + v2.y + v3.y + 2.f * bb.y) * sc, 0.f);
            v.z = fmaxf((v0.z + v1.z + v2.z + v3.z + 2.f * bb.z) * sc, 0.f);
            v.w = fmaxf((v0.w + v1.w + v2.w + v3.w + 2.f * bb.w) * sc, 0.f);
            ((float4*)out)[(size_t)p * 50 + oq2] = v;
        }
    }
}

extern "C" void kernel_launch(void* const* d_in, const int* in_sizes, int n_in,
                              void* d_out, int out_size, void* d_ws, size_t ws_size,
                              hipStream_t stream) {
    const int*   adj   = (const int*)d_in[0];
    const int*   words = (const int*)d_in[1];
    const int*   pos   = (const int*)d_in[2];
    const int*   ner   = (const int*)d_in[3];
    const float* emb   = (const float*)d_in[4];
    const float* pose  = (const float*)d_in[5];
    const float* nere  = (const float*)d_in[6];
    const float* dep   = (const float*)d_in[7];
    const float* Wp    = (const float*)d_in[8];
    const float* bp    = (const float*)d_in[9];
    const float* W0    = (const float*)d_in[10];
    const float* b0    = (const float*)d_in[11];
    const float* W1    = (const float*)d_in[12];
    const float* b1    = (const float*)d_in[13];
    float* out = (float*)d_out;
    float* ws  = (float*)d_ws;

    float*    xA     = ws;                        // 640,000
    float*    xB     = ws + 640000;               // 640,000
    float*    WpT    = ws + 1280000;              //  72,000
    float*    W0T    = ws + 1352000;              //  40,000
    float*    W1T    = ws + 1392000;              //  40,000
    float*    invd   = ws + 1432000;              //   3,200
    uint2*    depp_g = (uint2*)(ws + 1435200);    //   2,000 uint2
    unsigned* adjp_g = (unsigned*)(ws + 1439200); //  80,000 u32

    wpt_kernel<<<36, 512, 0, stream>>>(Wp, WpT);
    embed_prep_kernel<<<633, 512, 0, stream>>>(words, pos, ner, emb, pose, nere,
                                               WpT, bp, adj, dep, W0, W1, W0T, W1T,
                                               depp_g, adjp_g,
                                               xA, invd, out + (size_t)NP * DD);
    layer_kernel<<<dim3(NT, BB), 1024, 0, stream>>>(xA, depp_g, adjp_g, W0T, b0, invd, xB);
    layer_kernel<<<dim3(NT, BB), 1024, 0, stream>>>(xB, depp_g, adjp_g, W1T, b1, invd, out);
}